// Round 8
// baseline (347.122 us; speedup 1.0000x reference)
//
#include <hip/hip_runtime.h>
#include <hip/hip_bf16.h>
#include <type_traits>

typedef __attribute__((ext_vector_type(8))) short short8;
typedef __attribute__((ext_vector_type(4))) float f32x4;
typedef unsigned short u16;
typedef unsigned int u32;

typedef const __attribute__((address_space(1))) u32* gp1_t;
typedef __attribute__((address_space(3))) u32* lp3_t;

#define VMW(n) asm volatile("s_waitcnt vmcnt(" #n ")" ::: "memory")
#define SCHB() __builtin_amdgcn_sched_barrier(0)
#define SBAR() __builtin_amdgcn_s_barrier()

__device__ __forceinline__ float bf2f(u16 u) {
    union { unsigned int i; float f; } x; x.i = ((unsigned int)u) << 16; return x.f;
}
// hardware RNE f32->bf16 (compiler packs pairs into v_cvt_pk_bf16_f32)
__device__ __forceinline__ u16 f2bf(float f) {
    union { __hip_bfloat16 h; u16 u; } c; c.h = __float2bfloat16(f); return c.u;
}
__device__ __forceinline__ short8 cvt8(float4 v0, float4 v1) {
    union { u16 u[8]; short8 s; } p;
    p.u[0] = f2bf(v0.x); p.u[1] = f2bf(v0.y); p.u[2] = f2bf(v0.z); p.u[3] = f2bf(v0.w);
    p.u[4] = f2bf(v1.x); p.u[5] = f2bf(v1.y); p.u[6] = f2bf(v1.z); p.u[7] = f2bf(v1.w);
    return p.s;
}
// async global->LDS, 16B per lane; LDS ptr is the WAVE base (lane*16 added by HW)
__device__ __forceinline__ void gload_lds16(const void* g, void* l) {
    __builtin_amdgcn_global_load_lds((gp1_t)g, (lp3_t)l, 16, 0, 0);
}

// ---------------------------------------------------------------------------
// Fused weight transpose+concat+bf16: 6 jobs in one launch.
// ---------------------------------------------------------------------------
struct TCJobs {
    const float* A[6];
    const float* Bm[6];
    u16* out[6];
    int N[6];
    int Ka[6];
};

__global__ void transcat6_k(TCJobs j) {
    int jid = blockIdx.y;
    int i = blockIdx.x * 256 + threadIdx.x;
    int N = j.N[jid];
    if (i >= N * 512) return;
    int n = i >> 9, k = i & 511, Ka = j.Ka[jid];
    float v = (k < Ka) ? j.A[jid][k * N + n] : j.Bm[jid][(k - Ka) * N + n];
    j.out[jid][i] = f2bf(v);
}

// ---------------------------------------------------------------------------
// Merged-job MFMA GEMM, BK=32, 3-buffer LDS, COUNTED-vmcnt pipeline (T4):
//   prologue: STAGE(0),STAGE(1)
//   step t:   STAGE(t+2) ; vmcnt(12|8) ; s_barrier ; compute(t) ; s_barrier
// Loads stay in flight across barriers (never drained to 0 in the loop) —
// the documented escape from the drain-all ~9%-MfmaUtil regime (m218, AITER).
// Per-wave DMA ledger: f32 stage = 6 ops -> waits 12/6/0; bf16 = 4 -> 8/4/0.
// 128x128 tile, 4 waves; LDS 72 KB (f32A) / 48 KB (bf16) -> 2 / 3 blocks/CU.
// All staging via global_load_lds_dwordx4 with XOR-involution pre-swizzled
// source + matching read XOR (rule #21).
// ---------------------------------------------------------------------------
struct GJob {
    const void* A;      // [M,512] f32 or bf16
    const u16* WT;      // [N,512] bf16 (transposed-concat weights)
    const float* bias;  // or nullptr
    void* C;            // [M,N] bf16 or f32
    int M;
    int nct;            // col tiles; N = nct*128
    int toff;           // first tile index of this job (ascending)
};
struct GJobs4 { GJob j[4]; };

template <int NJ, bool F32A, int ACT, bool OF32>
__global__ __launch_bounds__(256, 2) void gemm_k(GJobs4 js) {
    const int K = 512;
    constexpr int ASZ = F32A ? 16384 : 8192;     // A bytes per buffer
    __shared__ __align__(1024) char As[3 * ASZ];
    __shared__ __align__(1024) char Bs[3 * 8192];
    const int t = threadIdx.x;
    const int lane = t & 63;
    const int wid = t >> 6;
    const int wr = wid >> 1, wc = wid & 1;       // wave tile: (wr*64, wc*64)
    const int lr = lane & 15;

    // m204 bijective XCD-chunked tile swizzle over the merged grid
    const int nwg = gridDim.x, p = blockIdx.x;
    const int q = nwg >> 3, rr = nwg & 7;
    const int xcd = p & 7, idx = p >> 3;
    const int L = (xcd < rr ? xcd * (q + 1) : rr * (q + 1) + (xcd - rr) * q) + idx;

    // job select (NJ small, table sorted by toff)
    GJob jb = js.j[0];
    #pragma unroll
    for (int k = 1; k < NJ; ++k) if (L >= js.j[k].toff) jb = js.j[k];
    const int tl = L - jb.toff;
    const int rt = (jb.nct == 2) ? (tl >> 1) : tl;
    const int ct = (jb.nct == 2) ? (tl & 1) : 0;
    const int row_base = rt * 128, col_base = ct * 128;
    const int M = jb.M, N = jb.nct << 7;

    f32x4 acc[4][4] = {};

    // ---- stage one K-step tile pair into buffer pb ----
    auto stage = [&](int kt, int pb) {
        char* bs = &Bs[pb * 8192];
        #pragma unroll
        for (int i = 0; i < 2; ++i) {            // B: 128 rows x 32 bf16, 2 DMA
            int slot = wid * 2 + i;              // 0..7, 16 rows each
            int rl = slot * 16 + (lane >> 2);    // 0..127
            int cc = (lane & 3) ^ (rl & 3);      // involution chunk swizzle
            gload_lds16(&jb.WT[(size_t)(col_base + rl) * K + kt + cc * 8],
                        &bs[slot * 1024]);
        }
        char* as = &As[pb * ASZ];
        if constexpr (F32A) {
            #pragma unroll
            for (int i = 0; i < 4; ++i) {        // A f32: 128 x 32, 4 DMA
                int slot = wid * 4 + i;          // 0..15, 8 rows each
                int rl = slot * 8 + (lane >> 3);
                int sc = (lane & 7) ^ (rl & 7);
                int gr = row_base + rl; if (gr >= M) gr = M - 1;
                gload_lds16(&((const float*)jb.A)[(size_t)gr * K + kt + sc * 4],
                            &as[slot * 1024]);
            }
        } else {
            #pragma unroll
            for (int i = 0; i < 2; ++i) {        // A bf16: 128 x 32, 2 DMA
                int slot = wid * 2 + i;
                int rl = slot * 16 + (lane >> 2);
                int cc = (lane & 3) ^ (rl & 3);
                int gr = row_base + rl; if (gr >= M) gr = M - 1;
                gload_lds16(&((const u16*)jb.A)[(size_t)gr * K + kt + cc * 8],
                            &as[slot * 1024]);
            }
        }
    };

    // ---- compute one K-step from buffer pb: 16 MFMA/wave ----
    auto compute = [&](int pb) {
        const char* as = &As[pb * ASZ];
        const char* bs = &Bs[pb * 8192];
        const int g = lane >> 4;                 // 8-elem k-group (0..3)
        short8 a[4], b[4];
        #pragma unroll
        for (int ni = 0; ni < 4; ++ni) {
            int r = wc * 64 + ni * 16 + lr;
            b[ni] = *(const short8*)&bs[r * 64 + ((g ^ (r & 3)) * 16)];
        }
        #pragma unroll
        for (int mi = 0; mi < 4; ++mi) {
            int r = wr * 64 + mi * 16 + lr;
            if constexpr (F32A) {
                float4 v0 = *(const float4*)&as[r * 128 + (((2 * g) ^ (r & 7)) * 16)];
                float4 v1 = *(const float4*)&as[r * 128 + (((2 * g + 1) ^ (r & 7)) * 16)];
                a[mi] = cvt8(v0, v1);
            } else {
                a[mi] = *(const short8*)&as[r * 64 + ((g ^ (r & 3)) * 16)];
            }
        }
        #pragma unroll
        for (int mi = 0; mi < 4; ++mi)
            #pragma unroll
            for (int ni = 0; ni < 4; ++ni)
                acc[mi][ni] = __builtin_amdgcn_mfma_f32_16x16x32_bf16(
                    a[mi], b[ni], acc[mi][ni], 0, 0, 0);
    };

    // ---- pipeline: 16 K-steps, prefetch depth 2, counted vmcnt ----
    stage(0, 0);
    stage(32, 1);
    int pb2 = 2;                                 // buffer for stage(t+2)
    int pbc = 0;                                 // buffer for compute(t)
    for (int tt = 0; tt < 14; ++tt) {
        stage((tt + 2) << 5, pb2);
        if constexpr (F32A) VMW(12); else VMW(8);
        SCHB(); SBAR(); SCHB();
        compute(pbc);
        SBAR();
        pb2 = (pb2 == 2) ? 0 : pb2 + 1;
        pbc = (pbc == 2) ? 0 : pbc + 1;
    }
    // t = 14 (one stage still in flight)
    if constexpr (F32A) VMW(6); else VMW(4);
    SCHB(); SBAR(); SCHB();
    compute(pbc);
    SBAR();
    pbc = (pbc == 2) ? 0 : pbc + 1;
    // t = 15 (drain)
    VMW(0);
    SCHB(); SBAR(); SCHB();
    compute(pbc);

    // epilogue: C/D layout col=lane&15, row=(lane>>4)*4+reg  [m89 verified]
    #pragma unroll
    for (int mi = 0; mi < 4; ++mi) {
        int row0 = row_base + wr * 64 + mi * 16 + ((lane >> 4) << 2);
        #pragma unroll
        for (int ni = 0; ni < 4; ++ni) {
            int col = col_base + wc * 64 + ni * 16 + lr;
            float bv = jb.bias ? jb.bias[col] : 0.f;
            #pragma unroll
            for (int r = 0; r < 4; ++r) {
                int row = row0 + r;
                if (row < M) {
                    float x = acc[mi][ni][r] + bv;
                    if (ACT == 1) x = fmaxf(x, 0.f);
                    if (ACT == 2) x = 1.f / (1.f + __expf(-x));
                    if constexpr (OF32)
                        ((float*)jb.C)[(size_t)row * N + col] = x;
                    else
                        ((u16*)jb.C)[(size_t)row * N + col] = f2bf(x);
                }
            }
        }
    }
}

// ---------------------------------------------------------------------------
// Merged build_x: X[r] = [ selfP[sidx[r]] (256 bf16) | mean_f nbP[nidx[r*10+f]] ]
// Half-wave (32 lanes) per row, 16 B/lane. null idx means identity.
// ---------------------------------------------------------------------------
struct BJob {
    u16* X;
    const u16* selfP;
    const int* sidx;
    const u16* nbP;
    const int* nidx;
    int roff;           // first global row of this job (ascending)
};
struct BJobs4 { BJob j[4]; };

template <int NJ>
__global__ void build_xm_k(BJobs4 bj, int total) {
    int gw = (int)((blockIdx.x * blockDim.x + threadIdx.x) >> 5);
    int hl = threadIdx.x & 31;
    if (gw >= total) return;
    BJob jb = bj.j[0];
    #pragma unroll
    for (int k = 1; k < NJ; ++k) if (gw >= bj.j[k].roff) jb = bj.j[k];
    int r = gw - jb.roff;

    int c8 = hl * 8;
    int sr = jb.sidx ? jb.sidx[r] : r;
    short8 sv = *(const short8*)&jb.selfP[(size_t)sr * 256 + c8];
    *(short8*)&jb.X[(size_t)r * 512 + c8] = sv;

    float s[8] = {};
    #pragma unroll
    for (int f = 0; f < 10; ++f) {
        int nr = jb.nidx ? jb.nidx[r * 10 + f] : r * 10 + f;
        short8 nv = *(const short8*)&jb.nbP[(size_t)nr * 256 + c8];
        #pragma unroll
        for (int jj = 0; jj < 8; ++jj) s[jj] += bf2f((u16)nv[jj]);
    }
    union { u16 u[8]; short8 v; } o;
    #pragma unroll
    for (int jj = 0; jj < 8; ++jj) o.u[jj] = f2bf(s[jj] * 0.1f);
    *(short8*)&jb.X[(size_t)r * 512 + 256 + c8] = o.v;
}

// ---------------------------------------------------------------------------
// logits[b] = sum_k hu[b,k]*hi[b,k]*wlin[k] + blin    (one wave per b)
// ---------------------------------------------------------------------------
__global__ void logits_k(const float* __restrict__ hu, const float* __restrict__ hi,
                         const float* __restrict__ wlin, const float* __restrict__ blin,
                         float* __restrict__ out, int Bn) {
    int w = (blockIdx.x * blockDim.x + threadIdx.x) >> 6;
    int lane = threadIdx.x & 63;
    if (w >= Bn) return;
    float s = 0.f;
    #pragma unroll
    for (int k = lane; k < 128; k += 64)
        s += hu[(size_t)w * 128 + k] * hi[(size_t)w * 128 + k] * wlin[k];
    #pragma unroll
    for (int off = 32; off > 0; off >>= 1) s += __shfl_down(s, off, 64);
    if (lane == 0) out[w] = s + blin[0];
}

// ---------------------------------------------------------------------------
extern "C" void kernel_launch(void* const* d_in, const int* in_sizes, int n_in,
                              void* d_out, int out_size, void* d_ws, size_t ws_size,
                              hipStream_t stream) {
    const float* user_feat = (const float*)d_in[0];
    const float* item_feat = (const float*)d_in[1];
    const float* W_pu = (const float*)d_in[2];
    const float* b_pu = (const float*)d_in[3];
    const float* W_pi = (const float*)d_in[4];
    const float* b_pi = (const float*)d_in[5];
    const float* u_self0 = (const float*)d_in[6];
    const float* u_agg0 = (const float*)d_in[7];
    const float* u_self1 = (const float*)d_in[8];
    const float* u_agg1 = (const float*)d_in[9];
    const float* i_self0 = (const float*)d_in[10];
    const float* i_agg0 = (const float*)d_in[11];
    const float* i_self1 = (const float*)d_in[12];
    const float* i_agg1 = (const float*)d_in[13];
    const float* W_lin = (const float*)d_in[14];
    const float* b_lin = (const float*)d_in[15];
    const int* src_h0 = (const int*)d_in[16];
    const int* src_h1 = (const int*)d_in[17];
    const int* src_h2 = (const int*)d_in[18];
    const int* dst_h0 = (const int*)d_in[19];
    const int* dst_h1 = (const int*)d_in[20];
    const int* dst_h2 = (const int*)d_in[21];
    float* out = (float*)d_out;

    const int NU = 50000, NI = 100000, B = 4096, BF = 40960;

    char* ws = (char*)d_ws;
    size_t off = 0;
    auto alloc = [&](size_t bytes) -> void* {
        void* p = ws + off;
        off += (bytes + 255) & ~(size_t)255;
        return p;
    };
    u16* Pu   = (u16*)alloc((size_t)NU * 256 * 2);
    u16* Pi   = (u16*)alloc((size_t)NI * 256 * 2);
    u16* X1a  = (u16*)alloc((size_t)BF * 512 * 2);
    u16* X1b  = (u16*)alloc((size_t)BF * 512 * 2);
    u16* G1a  = (u16*)alloc((size_t)BF * 256 * 2);
    u16* G1b  = (u16*)alloc((size_t)BF * 256 * 2);
    u16* X0a  = (u16*)alloc((size_t)B * 512 * 2);
    u16* X0b  = (u16*)alloc((size_t)B * 512 * 2);
    u16* G0a  = (u16*)alloc((size_t)B * 256 * 2);
    u16* G0b  = (u16*)alloc((size_t)B * 256 * 2);
    u16* X2a  = (u16*)alloc((size_t)B * 512 * 2);
    u16* X2b  = (u16*)alloc((size_t)B * 512 * 2);
    float* Hu = (float*)alloc((size_t)B * 128 * 4);
    float* Hi = (float*)alloc((size_t)B * 128 * 4);
    u16* WpuT = (u16*)alloc(256 * 512 * 2);
    u16* WpiT = (u16*)alloc(256 * 512 * 2);
    u16* W0uT = (u16*)alloc(256 * 512 * 2);
    u16* W0iT = (u16*)alloc(256 * 512 * 2);
    u16* W1uT = (u16*)alloc(128 * 512 * 2);
    u16* W1iT = (u16*)alloc(128 * 512 * 2);

    // --- 1. weight prep: 6 transposed-concat bf16 layouts, one launch ---
    TCJobs tj;
    tj.A[0] = W_pu;    tj.Bm[0] = W_pu;    tj.out[0] = WpuT; tj.N[0] = 256; tj.Ka[0] = 512;
    tj.A[1] = W_pi;    tj.Bm[1] = W_pi;    tj.out[1] = WpiT; tj.N[1] = 256; tj.Ka[1] = 512;
    tj.A[2] = u_self0; tj.Bm[2] = u_agg0;  tj.out[2] = W0uT; tj.N[2] = 256; tj.Ka[2] = 256;
    tj.A[3] = i_self0; tj.Bm[3] = i_agg0;  tj.out[3] = W0iT; tj.N[3] = 256; tj.Ka[3] = 256;
    tj.A[4] = u_self1; tj.Bm[4] = u_agg1;  tj.out[4] = W1uT; tj.N[4] = 128; tj.Ka[4] = 256;
    tj.A[5] = i_self1; tj.Bm[5] = i_agg1;  tj.out[5] = W1iT; tj.N[5] = 128; tj.Ka[5] = 256;
    transcat6_k<<<dim3(512, 6), 256, 0, stream>>>(tj);

    // --- 2. both projections, one launch: P = sigmoid(feat @ W + b) ---
    const int ptu = ((NU + 127) / 128) * 2;          // 782
    const int pti = ((NI + 127) / 128) * 2;          // 1564
    GJobs4 pj;
    pj.j[0] = {user_feat, WpuT, b_pu, Pu, NU, 2, 0};
    pj.j[1] = {item_feat, WpiT, b_pi, Pi, NI, 2, ptu};
    pj.j[2] = pj.j[1]; pj.j[3] = pj.j[1];
    gemm_k<2, true, 2, false><<<ptu + pti, 256, 0, stream>>>(pj);

    // --- 3. all four gather/mean builds, one launch ---
    BJobs4 b1;
    b1.j[0] = {X1a, Pi, src_h1, Pu, src_h2, 0};
    b1.j[1] = {X1b, Pu, dst_h1, Pi, dst_h2, BF};
    b1.j[2] = {X0a, Pu, src_h0, Pi, src_h1, 2 * BF};
    b1.j[3] = {X0b, Pi, dst_h0, Pu, dst_h1, 2 * BF + B};
    const int tot1 = 2 * BF + 2 * B;                 // 90112
    build_xm_k<4><<<tot1 / 8, 256, 0, stream>>>(b1, tot1);

    // --- 4. all four SAGE layer-0 GEMMs (relu, bf16 out), one launch ---
    GJobs4 sj;
    sj.j[0] = {X1a, W0uT, nullptr, G1a, BF, 2, 0};
    sj.j[1] = {X1b, W0iT, nullptr, G1b, BF, 2, 640};
    sj.j[2] = {X0a, W0uT, nullptr, G0a, B, 2, 1280};
    sj.j[3] = {X0b, W0iT, nullptr, G0b, B, 2, 1344};
    gemm_k<4, false, 1, false><<<1408, 256, 0, stream>>>(sj);

    // --- 5. hop-0 concat builds (identity indices), one launch ---
    BJobs4 b2;
    b2.j[0] = {X2a, G0a, nullptr, G1a, nullptr, 0};
    b2.j[1] = {X2b, G0b, nullptr, G1b, nullptr, B};
    b2.j[2] = b2.j[1]; b2.j[3] = b2.j[1];
    build_xm_k<2><<<(2 * B) / 8, 256, 0, stream>>>(b2, 2 * B);

    // --- 6. both final GEMMs (no act, f32 out), one launch ---
    GJobs4 fj;
    fj.j[0] = {X2a, W1uT, nullptr, Hu, B, 1, 0};
    fj.j[1] = {X2b, W1iT, nullptr, Hi, B, 1, 32};
    fj.j[2] = fj.j[1]; fj.j[3] = fj.j[1];
    gemm_k<2, false, 0, true><<<64, 256, 0, stream>>>(fj);

    // --- 7. final logits ---
    logits_k<<<B / 4, 256, 0, stream>>>(Hu, Hi, W_lin, b_lin, out, B);
}

// Round 9
// 304.228 us; speedup vs baseline: 1.1410x; 1.1410x over previous
//
#include <hip/hip_runtime.h>
#include <hip/hip_bf16.h>
#include <type_traits>

typedef __attribute__((ext_vector_type(8))) short short8;
typedef __attribute__((ext_vector_type(4))) float f32x4;
typedef unsigned short u16;
typedef unsigned int u32;

typedef const __attribute__((address_space(1))) u32* gp1_t;
typedef __attribute__((address_space(3))) u32* lp3_t;

__device__ __forceinline__ float bf2f(u16 u) {
    union { unsigned int i; float f; } x; x.i = ((unsigned int)u) << 16; return x.f;
}
// hardware RNE f32->bf16 (compiler packs pairs into v_cvt_pk_bf16_f32)
__device__ __forceinline__ u16 f2bf(float f) {
    union { __hip_bfloat16 h; u16 u; } c; c.h = __float2bfloat16(f); return c.u;
}
__device__ __forceinline__ short8 cvt8(float4 v0, float4 v1) {
    union { u16 u[8]; short8 s; } p;
    p.u[0] = f2bf(v0.x); p.u[1] = f2bf(v0.y); p.u[2] = f2bf(v0.z); p.u[3] = f2bf(v0.w);
    p.u[4] = f2bf(v1.x); p.u[5] = f2bf(v1.y); p.u[6] = f2bf(v1.z); p.u[7] = f2bf(v1.w);
    return p.s;
}
// async global->LDS, 16B per lane; LDS ptr is the WAVE base (lane*16 added by HW)
__device__ __forceinline__ void gload_lds16(const void* g, void* l) {
    __builtin_amdgcn_global_load_lds((gp1_t)g, (lp3_t)l, 16, 0, 0);
}

// ---------------------------------------------------------------------------
// Fused weight transpose+concat+bf16: 6 jobs in one launch.
// ---------------------------------------------------------------------------
struct TCJobs {
    const float* A[6];
    const float* Bm[6];
    u16* out[6];
    int N[6];
    int Ka[6];
};

__global__ void transcat6_k(TCJobs j) {
    int jid = blockIdx.y;
    int i = blockIdx.x * 256 + threadIdx.x;
    int N = j.N[jid];
    if (i >= N * 512) return;
    int n = i >> 9, k = i & 511, Ka = j.Ka[jid];
    float v = (k < Ka) ? j.A[jid][k * N + n] : j.Bm[jid][(k - Ka) * N + n];
    j.out[jid][i] = f2bf(v);
}

// ---------------------------------------------------------------------------
// Merged-job MFMA GEMM, tile 128 x (WC*64), BK=32, full-DMA single-buffered
// staging (R6/R7 structure — the best measured). WC=4: N=256 per block ->
// every A row-panel is HBM/L2-fetched exactly ONCE (halves VMEM read traffic
// vs nct=2). 2*WC waves, each owning a 64x64 sub-tile.
// B / bf16-A staged with XOR involution cc=(lane&3)^((rl>>1)&3) and read with
// the matching q=g^((r>>1)&3): 8 distinct 16B slots per 16-lane group ->
// 2-way bank aliasing (free, m136). f32-A keeps the R3..R7-verified 8-chunk
// involution. All staging via global_load_lds_dwordx4 (rule #21 both-sides).
// ---------------------------------------------------------------------------
struct GJob {
    const void* A;      // [M,512] f32 or bf16
    const u16* WT;      // [N,512] bf16 (transposed-concat weights), N = WC*64
    const float* bias;  // or nullptr
    void* C;            // [M,N] bf16 or f32
    int M;
    int toff;           // first 128-row tile index of this job (ascending)
};
struct GJobs4 { GJob j[4]; };

template <int NJ, int WC, bool F32A, int ACT, bool OF32>
__global__ __launch_bounds__(WC * 128, 4) void gemm_k(GJobs4 js) {
    const int K = 512;
    const int N = WC * 64;
    __shared__ __align__(1024) char As[F32A ? 16384 : 8192];  // 128 x 32
    __shared__ __align__(1024) char Bs[WC * 4096];            // N x 32
    const int t = threadIdx.x;
    const int lane = t & 63;
    const int wid = t >> 6;                      // 0 .. 2*WC-1
    const int wr = wid / WC, wc = wid % WC;      // wave tile: (wr*64, wc*64)
    const int lr = lane & 15;

    // m204 bijective XCD-chunked tile swizzle over the merged grid
    const int nwg = gridDim.x, p = blockIdx.x;
    const int q = nwg >> 3, rr = nwg & 7;
    const int xcd = p & 7, idx = p >> 3;
    const int L = (xcd < rr ? xcd * (q + 1) : rr * (q + 1) + (xcd - rr) * q) + idx;

    // job select (NJ small, table sorted by toff)
    GJob jb = js.j[0];
    #pragma unroll
    for (int k = 1; k < NJ; ++k) if (L >= js.j[k].toff) jb = js.j[k];
    const int row_base = (L - jb.toff) * 128;
    const int M = jb.M;

    f32x4 acc[4][4] = {};

    for (int kt = 0; kt < K; kt += 32) {
        // ---- stage B tile: N rows x 32 bf16, 2 DMA/wave ----
        #pragma unroll
        for (int i = 0; i < 2; ++i) {
            int slot = wid * 2 + i;                  // 0 .. 4*WC-1, 16 rows each
            int rl = slot * 16 + (lane >> 2);        // 0 .. N-1
            int cc = (lane & 3) ^ ((rl >> 1) & 3);   // involution chunk swizzle
            gload_lds16(&jb.WT[(size_t)rl * K + kt + cc * 8], &Bs[slot * 1024]);
        }
        // ---- stage A tile: 128 rows x 32 elems ----
        if constexpr (F32A) {
            #pragma unroll
            for (int i = 0; i < 16 / (2 * WC); ++i) {    // 16 slots of 8 rows
                int slot = wid * (16 / (2 * WC)) + i;
                int rl = slot * 8 + (lane >> 3);          // 0..127
                int sc = (lane & 7) ^ (rl & 7);           // verified f32 involution
                int gr = row_base + rl; if (gr >= M) gr = M - 1;
                gload_lds16(&((const float*)jb.A)[(size_t)gr * K + kt + sc * 4],
                            &As[slot * 1024]);
            }
        } else {
            #pragma unroll
            for (int i = 0; i < 8 / (2 * WC); ++i) {     // 8 slots of 16 rows
                int slot = wid * (8 / (2 * WC)) + i;
                int rl = slot * 16 + (lane >> 2);         // 0..127
                int cc = (lane & 3) ^ ((rl >> 1) & 3);
                int gr = row_base + rl; if (gr >= M) gr = M - 1;
                gload_lds16(&((const u16*)jb.A)[(size_t)gr * K + kt + cc * 8],
                            &As[slot * 1024]);
            }
        }
        __syncthreads();

        // ---- compute: 16 MFMA per wave per K-step ----
        {
            const int g = lane >> 4;                 // 8-elem k-group (0..3)
            short8 a[4], b[4];
            #pragma unroll
            for (int ni = 0; ni < 4; ++ni) {
                int r = wc * 64 + ni * 16 + lr;
                b[ni] = *(const short8*)&Bs[r * 64 + ((g ^ ((r >> 1) & 3)) * 16)];
            }
            #pragma unroll
            for (int mi = 0; mi < 4; ++mi) {
                int r = wr * 64 + mi * 16 + lr;
                if constexpr (F32A) {
                    float4 v0 = *(const float4*)&As[r * 128 + (((2 * g) ^ (r & 7)) * 16)];
                    float4 v1 = *(const float4*)&As[r * 128 + (((2 * g + 1) ^ (r & 7)) * 16)];
                    a[mi] = cvt8(v0, v1);
                } else {
                    a[mi] = *(const short8*)&As[r * 64 + ((g ^ ((r >> 1) & 3)) * 16)];
                }
            }
            #pragma unroll
            for (int mi = 0; mi < 4; ++mi)
                #pragma unroll
                for (int ni = 0; ni < 4; ++ni)
                    acc[mi][ni] = __builtin_amdgcn_mfma_f32_16x16x32_bf16(
                        a[mi], b[ni], acc[mi][ni], 0, 0, 0);
        }
        __syncthreads();
    }

    // epilogue: C/D layout col=lane&15, row=(lane>>4)*4+reg  [m89 verified]
    #pragma unroll
    for (int mi = 0; mi < 4; ++mi) {
        int row0 = row_base + wr * 64 + mi * 16 + ((lane >> 4) << 2);
        #pragma unroll
        for (int ni = 0; ni < 4; ++ni) {
            int col = wc * 64 + ni * 16 + lr;
            float bv = jb.bias ? jb.bias[col] : 0.f;
            #pragma unroll
            for (int r = 0; r < 4; ++r) {
                int row = row0 + r;
                if (row < M) {
                    float x = acc[mi][ni][r] + bv;
                    if (ACT == 1) x = fmaxf(x, 0.f);
                    if (ACT == 2) x = 1.f / (1.f + __expf(-x));
                    if constexpr (OF32)
                        ((float*)jb.C)[(size_t)row * N + col] = x;
                    else
                        ((u16*)jb.C)[(size_t)row * N + col] = f2bf(x);
                }
            }
        }
    }
}

// ---------------------------------------------------------------------------
// Merged build_x: X[r] = [ selfP[sidx[r]] (256 bf16) | mean_f nbP[nidx[r*10+f]] ]
// Half-wave (32 lanes) per row, 16 B/lane. null idx means identity.
// ---------------------------------------------------------------------------
struct BJob {
    u16* X;
    const u16* selfP;
    const int* sidx;
    const u16* nbP;
    const int* nidx;
    int roff;           // first global row of this job (ascending)
};
struct BJobs4 { BJob j[4]; };

template <int NJ>
__global__ void build_xm_k(BJobs4 bj, int total) {
    int gw = (int)((blockIdx.x * blockDim.x + threadIdx.x) >> 5);
    int hl = threadIdx.x & 31;
    if (gw >= total) return;
    BJob jb = bj.j[0];
    #pragma unroll
    for (int k = 1; k < NJ; ++k) if (gw >= bj.j[k].roff) jb = bj.j[k];
    int r = gw - jb.roff;

    int c8 = hl * 8;
    int sr = jb.sidx ? jb.sidx[r] : r;
    short8 sv = *(const short8*)&jb.selfP[(size_t)sr * 256 + c8];
    *(short8*)&jb.X[(size_t)r * 512 + c8] = sv;

    float s[8] = {};
    #pragma unroll
    for (int f = 0; f < 10; ++f) {
        int nr = jb.nidx ? jb.nidx[r * 10 + f] : r * 10 + f;
        short8 nv = *(const short8*)&jb.nbP[(size_t)nr * 256 + c8];
        #pragma unroll
        for (int jj = 0; jj < 8; ++jj) s[jj] += bf2f((u16)nv[jj]);
    }
    union { u16 u[8]; short8 v; } o;
    #pragma unroll
    for (int jj = 0; jj < 8; ++jj) o.u[jj] = f2bf(s[jj] * 0.1f);
    *(short8*)&jb.X[(size_t)r * 512 + 256 + c8] = o.v;
}

// ---------------------------------------------------------------------------
// logits[b] = sum_k hu[b,k]*hi[b,k]*wlin[k] + blin    (one wave per b)
// ---------------------------------------------------------------------------
__global__ void logits_k(const float* __restrict__ hu, const float* __restrict__ hi,
                         const float* __restrict__ wlin, const float* __restrict__ blin,
                         float* __restrict__ out, int Bn) {
    int w = (blockIdx.x * blockDim.x + threadIdx.x) >> 6;
    int lane = threadIdx.x & 63;
    if (w >= Bn) return;
    float s = 0.f;
    #pragma unroll
    for (int k = lane; k < 128; k += 64)
        s += hu[(size_t)w * 128 + k] * hi[(size_t)w * 128 + k] * wlin[k];
    #pragma unroll
    for (int off = 32; off > 0; off >>= 1) s += __shfl_down(s, off, 64);
    if (lane == 0) out[w] = s + blin[0];
}

// ---------------------------------------------------------------------------
extern "C" void kernel_launch(void* const* d_in, const int* in_sizes, int n_in,
                              void* d_out, int out_size, void* d_ws, size_t ws_size,
                              hipStream_t stream) {
    const float* user_feat = (const float*)d_in[0];
    const float* item_feat = (const float*)d_in[1];
    const float* W_pu = (const float*)d_in[2];
    const float* b_pu = (const float*)d_in[3];
    const float* W_pi = (const float*)d_in[4];
    const float* b_pi = (const float*)d_in[5];
    const float* u_self0 = (const float*)d_in[6];
    const float* u_agg0 = (const float*)d_in[7];
    const float* u_self1 = (const float*)d_in[8];
    const float* u_agg1 = (const float*)d_in[9];
    const float* i_self0 = (const float*)d_in[10];
    const float* i_agg0 = (const float*)d_in[11];
    const float* i_self1 = (const float*)d_in[12];
    const float* i_agg1 = (const float*)d_in[13];
    const float* W_lin = (const float*)d_in[14];
    const float* b_lin = (const float*)d_in[15];
    const int* src_h0 = (const int*)d_in[16];
    const int* src_h1 = (const int*)d_in[17];
    const int* src_h2 = (const int*)d_in[18];
    const int* dst_h0 = (const int*)d_in[19];
    const int* dst_h1 = (const int*)d_in[20];
    const int* dst_h2 = (const int*)d_in[21];
    float* out = (float*)d_out;

    const int NU = 50000, NI = 100000, B = 4096, BF = 40960;

    char* ws = (char*)d_ws;
    size_t off = 0;
    auto alloc = [&](size_t bytes) -> void* {
        void* p = ws + off;
        off += (bytes + 255) & ~(size_t)255;
        return p;
    };
    u16* Pu   = (u16*)alloc((size_t)NU * 256 * 2);
    u16* Pi   = (u16*)alloc((size_t)NI * 256 * 2);
    u16* X1a  = (u16*)alloc((size_t)BF * 512 * 2);
    u16* X1b  = (u16*)alloc((size_t)BF * 512 * 2);
    u16* G1a  = (u16*)alloc((size_t)BF * 256 * 2);
    u16* G1b  = (u16*)alloc((size_t)BF * 256 * 2);
    u16* X0a  = (u16*)alloc((size_t)B * 512 * 2);
    u16* X0b  = (u16*)alloc((size_t)B * 512 * 2);
    u16* G0a  = (u16*)alloc((size_t)B * 256 * 2);
    u16* G0b  = (u16*)alloc((size_t)B * 256 * 2);
    u16* X2a  = (u16*)alloc((size_t)B * 512 * 2);
    u16* X2b  = (u16*)alloc((size_t)B * 512 * 2);
    float* Hu = (float*)alloc((size_t)B * 128 * 4);
    float* Hi = (float*)alloc((size_t)B * 128 * 4);
    u16* WpuT = (u16*)alloc(256 * 512 * 2);
    u16* WpiT = (u16*)alloc(256 * 512 * 2);
    u16* W0uT = (u16*)alloc(256 * 512 * 2);
    u16* W0iT = (u16*)alloc(256 * 512 * 2);
    u16* W1uT = (u16*)alloc(128 * 512 * 2);
    u16* W1iT = (u16*)alloc(128 * 512 * 2);

    // --- 1. weight prep: 6 transposed-concat bf16 layouts, one launch ---
    TCJobs tj;
    tj.A[0] = W_pu;    tj.Bm[0] = W_pu;    tj.out[0] = WpuT; tj.N[0] = 256; tj.Ka[0] = 512;
    tj.A[1] = W_pi;    tj.Bm[1] = W_pi;    tj.out[1] = WpiT; tj.N[1] = 256; tj.Ka[1] = 512;
    tj.A[2] = u_self0; tj.Bm[2] = u_agg0;  tj.out[2] = W0uT; tj.N[2] = 256; tj.Ka[2] = 256;
    tj.A[3] = i_self0; tj.Bm[3] = i_agg0;  tj.out[3] = W0iT; tj.N[3] = 256; tj.Ka[3] = 256;
    tj.A[4] = u_self1; tj.Bm[4] = u_agg1;  tj.out[4] = W1uT; tj.N[4] = 128; tj.Ka[4] = 256;
    tj.A[5] = i_self1; tj.Bm[5] = i_agg1;  tj.out[5] = W1iT; tj.N[5] = 128; tj.Ka[5] = 256;
    transcat6_k<<<dim3(512, 6), 256, 0, stream>>>(tj);

    // --- 2. both projections, one launch (WC=4: full N=256 per block) ---
    const int ptu = (NU + 127) / 128;                // 391
    const int pti = (NI + 127) / 128;                // 782
    GJobs4 pj;
    pj.j[0] = {user_feat, WpuT, b_pu, Pu, NU, 0};
    pj.j[1] = {item_feat, WpiT, b_pi, Pi, NI, ptu};
    pj.j[2] = pj.j[1]; pj.j[3] = pj.j[1];
    gemm_k<2, 4, true, 2, false><<<ptu + pti, 512, 0, stream>>>(pj);

    // --- 3. all four gather/mean builds, one launch ---
    BJobs4 b1;
    b1.j[0] = {X1a, Pi, src_h1, Pu, src_h2, 0};
    b1.j[1] = {X1b, Pu, dst_h1, Pi, dst_h2, BF};
    b1.j[2] = {X0a, Pu, src_h0, Pi, src_h1, 2 * BF};
    b1.j[3] = {X0b, Pi, dst_h0, Pu, dst_h1, 2 * BF + B};
    const int tot1 = 2 * BF + 2 * B;                 // 90112
    build_xm_k<4><<<tot1 / 8, 256, 0, stream>>>(b1, tot1);

    // --- 4. all four SAGE layer-0 GEMMs (relu, bf16 out), one launch ---
    GJobs4 sj;
    sj.j[0] = {X1a, W0uT, nullptr, G1a, BF, 0};
    sj.j[1] = {X1b, W0iT, nullptr, G1b, BF, 320};
    sj.j[2] = {X0a, W0uT, nullptr, G0a, B, 640};
    sj.j[3] = {X0b, W0iT, nullptr, G0b, B, 672};
    gemm_k<4, 4, false, 1, false><<<704, 512, 0, stream>>>(sj);

    // --- 5. hop-0 concat builds (identity indices), one launch ---
    BJobs4 b2;
    b2.j[0] = {X2a, G0a, nullptr, G1a, nullptr, 0};
    b2.j[1] = {X2b, G0b, nullptr, G1b, nullptr, B};
    b2.j[2] = b2.j[1]; b2.j[3] = b2.j[1];
    build_xm_k<2><<<(2 * B) / 8, 256, 0, stream>>>(b2, 2 * B);

    // --- 6. both final GEMMs (no act, f32 out, WC=2: N=128), one launch ---
    GJobs4 fj;
    fj.j[0] = {X2a, W1uT, nullptr, Hu, B, 0};
    fj.j[1] = {X2b, W1iT, nullptr, Hi, B, 32};
    fj.j[2] = fj.j[1]; fj.j[3] = fj.j[1];
    gemm_k<2, 2, false, 0, true><<<64, 256, 0, stream>>>(fj);

    // --- 7. final logits ---
    logits_k<<<B / 4, 256, 0, stream>>>(Hu, Hi, W_lin, b_lin, out, B);
}